// Round 1
// baseline (539.932 us; speedup 1.0000x reference)
//
#include <hip/hip_runtime.h>

// FractalAttention on gfx950: bf16 MFMA pipeline.
// Stages: cvt(fp32->bf16) -> GEMM QKV (scatter epilogue, Q prescaled, V transposed)
//         -> flash attention (16 heads, S=4096, D=64, phi^-h output scale)
//         -> GEMM O-proj (fp32 out + bias).

typedef unsigned short u16;
typedef unsigned int u32;
typedef __attribute__((ext_vector_type(8))) short short8;
typedef __attribute__((ext_vector_type(4))) float f32x4;
typedef __attribute__((ext_vector_type(4))) u16 u16x4;

#define KDIM 1024
// 0.125 (1/sqrt(64)) * log2(e): fold softmax scale + base-2 conversion into Q
#define QSCALE 0.18033688011112042f
// log2(phi)
#define LOG2PHI 0.6942419136306174f

__device__ __forceinline__ u16 f2bf(float f) {
  u32 u = __builtin_bit_cast(u32, f);
  u32 r = (u + 0x7fffu + ((u >> 16) & 1u)) >> 16;  // RNE
  return (u16)r;
}

__device__ __forceinline__ f32x4 fzero() {
  f32x4 z; z[0] = 0.f; z[1] = 0.f; z[2] = 0.f; z[3] = 0.f; return z;
}

// ---------------- fp32 -> bf16 convert, 4 elems/thread ----------------
__global__ __launch_bounds__(256) void cvt_kernel(const float* __restrict__ src,
                                                  u16* __restrict__ dst, int n4) {
  int i = blockIdx.x * 256 + threadIdx.x;
  if (i >= n4) return;
  f32x4 v = *(const f32x4*)(src + (size_t)i * 4);
  u16x4 o;
  o[0] = f2bf(v[0]); o[1] = f2bf(v[1]); o[2] = f2bf(v[2]); o[3] = f2bf(v[3]);
  *(u16x4*)(dst + (size_t)i * 4) = o;
}

// ---------------- GEMM C = A[M,1024] * B[N,1024]^T (both K-major bf16) ----------------
// 128x128 tile, BK=64, 4 waves (2x2), each wave 64x64 via 4x4 16x16x32 frags.
// MODE 0: QKV epilogue (bias add; Q prescaled bf16 [h][s][d]; K bf16 [h][s][d];
//         V transposed bf16 [h][d][s]).  MODE 1: fp32 out + bias.
template <int MODE>
__global__ __launch_bounds__(256) void gemm_bt(
    const u16* __restrict__ A, const u16* __restrict__ Bw,
    const float* __restrict__ bias0, const float* __restrict__ bias1,
    const float* __restrict__ bias2,
    u16* __restrict__ qo, u16* __restrict__ ko, u16* __restrict__ vto,
    float* __restrict__ co) {
  __shared__ u16 As[128 * 64];
  __shared__ u16 Bs[128 * 64];
  const int tid = threadIdx.x;
  const int w = tid >> 6, lane = tid & 63;
  const int wr = w >> 1, wc = w & 1;
  const int bm = blockIdx.x, bn = blockIdx.y;
  const int lr = lane & 15, lg = lane >> 4;
  const int srow8 = lane >> 3;   // staging: row within 8-row group
  const int schunk = lane & 7;   // staging: 16B chunk within row

  f32x4 acc[4][4];
#pragma unroll
  for (int m = 0; m < 4; ++m)
#pragma unroll
    for (int n = 0; n < 4; ++n) acc[m][n] = fzero();

  for (int kt = 0; kt < KDIM / 64; ++kt) {
    // ---- stage A,B tiles: global_load_lds width16, source pre-swizzled so that
    // reads with byte ^= ((row&7)<<4) see logical layout (rule 21: both sides).
#pragma unroll
    for (int it = 0; it < 4; ++it) {
      const int rowt = (w * 4 + it) * 8 + srow8;       // 0..127
      const int ck = schunk ^ (rowt & 7);              // swizzled source chunk
      const u16* sa = A + (size_t)(bm * 128 + rowt) * KDIM + kt * 64 + ck * 8;
      const u16* sb = Bw + (size_t)(bn * 128 + rowt) * KDIM + kt * 64 + ck * 8;
      auto ga = (const __attribute__((address_space(1))) u32*)sa;
      auto la = (__attribute__((address_space(3))) u32*)&As[(w * 4 + it) * 512];
      __builtin_amdgcn_global_load_lds(ga, la, 16, 0, 0);
      auto gb = (const __attribute__((address_space(1))) u32*)sb;
      auto lb = (__attribute__((address_space(3))) u32*)&Bs[(w * 4 + it) * 512];
      __builtin_amdgcn_global_load_lds(gb, lb, 16, 0, 0);
    }
    __syncthreads();
#pragma unroll
    for (int kk = 0; kk < 2; ++kk) {
      short8 af[4], bf[4];
#pragma unroll
      for (int m = 0; m < 4; ++m) {
        const int row = wr * 64 + m * 16 + lr;
        const int kb = kk * 64 + lg * 16;
        af[m] = *(const short8*)((const char*)As + row * 128 + (kb ^ ((row & 7) << 4)));
      }
#pragma unroll
      for (int n = 0; n < 4; ++n) {
        const int row = wc * 64 + n * 16 + lr;
        const int kb = kk * 64 + lg * 16;
        bf[n] = *(const short8*)((const char*)Bs + row * 128 + (kb ^ ((row & 7) << 4)));
      }
#pragma unroll
      for (int m = 0; m < 4; ++m)
#pragma unroll
        for (int n = 0; n < 4; ++n)
          acc[m][n] = __builtin_amdgcn_mfma_f32_16x16x32_bf16(af[m], bf[n], acc[m][n], 0, 0, 0);
    }
    __syncthreads();
  }

  // ---- epilogue; C/D layout: row=(lane>>4)*4+reg, col=lane&15
#pragma unroll
  for (int m = 0; m < 4; ++m) {
#pragma unroll
    for (int n = 0; n < 4; ++n) {
#pragma unroll
      for (int r = 0; r < 4; ++r) {
        const int srow = bm * 128 + wr * 64 + m * 16 + lg * 4 + r;
        const int col = bn * 128 + wc * 64 + n * 16 + lr;
        float v = acc[m][n][r];
        if (MODE == 0) {
          const int which = col >> 10;        // 0=q 1=k 2=v
          const int hd = col & 1023;
          const int h = hd >> 6, d = hd & 63;
          const float* bp = (which == 0) ? bias0 : (which == 1) ? bias1 : bias2;
          v += bp[hd];
          if (which == 0) {
            qo[(size_t)h * 262144 + (size_t)srow * 64 + d] = f2bf(v * QSCALE);
          } else if (which == 1) {
            ko[(size_t)h * 262144 + (size_t)srow * 64 + d] = f2bf(v);
          } else {
            vto[(size_t)h * 262144 + (size_t)d * 4096 + srow] = f2bf(v);  // V^T
          }
        } else {
          co[(size_t)srow * 1024 + col] = v + bias0[col];
        }
      }
    }
  }
}

// ---------------- flash attention ----------------
// grid = 16 heads * 64 q-tiles; 4 waves, each owns 16 q-rows; j-tiles of 64 keys.
// Q prescaled by 0.125*log2e -> softmax in base-2 (exp2). phi^-h folded into output.
__global__ __launch_bounds__(256) void attn_kernel(const u16* __restrict__ Q,
                                                   const u16* __restrict__ K,
                                                   const u16* __restrict__ VT,
                                                   u16* __restrict__ O) {
  __shared__ u16 Pl[4][16][72];  // per-wave P tile, padded stride 72 (2-way banks)
  const int tid = threadIdx.x;
  const int w = tid >> 6, lane = tid & 63;
  const int h = blockIdx.x >> 6, qt = blockIdx.x & 63;
  const int lr = lane & 15, lg = lane >> 4;
  const int qrow0 = qt * 64 + w * 16;

  const u16* qb = Q + (size_t)h * 262144 + (size_t)(qrow0 + lr) * 64 + lg * 8;
  short8 qf0 = *(const short8*)qb;          // d in [0,32)
  short8 qf1 = *(const short8*)(qb + 32);   // d in [32,64)

  const u16* kb = K + (size_t)h * 262144;
  const u16* vb = VT + (size_t)h * 262144;

  f32x4 o[4];
#pragma unroll
  for (int f = 0; f < 4; ++f) o[f] = fzero();
  float mrow[4] = {-1e30f, -1e30f, -1e30f, -1e30f};
  float lsum[4] = {0.f, 0.f, 0.f, 0.f};

  for (int j0 = 0; j0 < 4096; j0 += 64) {
    // S = Q K^T (base-2 logits already scaled)
    f32x4 s[4];
#pragma unroll
    for (int n = 0; n < 4; ++n) {
      const u16* kp = kb + (size_t)(j0 + n * 16 + lr) * 64 + lg * 8;
      short8 k0 = *(const short8*)kp;
      short8 k1 = *(const short8*)(kp + 32);
      s[n] = __builtin_amdgcn_mfma_f32_16x16x32_bf16(qf0, k0, fzero(), 0, 0, 0);
      s[n] = __builtin_amdgcn_mfma_f32_16x16x32_bf16(qf1, k1, s[n], 0, 0, 0);
    }
    // online softmax: rows live in 16-lane groups -> xor-shuffle reduce 1,2,4,8
    float mnew[4], alpha[4];
#pragma unroll
    for (int r = 0; r < 4; ++r) {
      float t = fmaxf(fmaxf(s[0][r], s[1][r]), fmaxf(s[2][r], s[3][r]));
      t = fmaxf(t, __shfl_xor(t, 1, 64));
      t = fmaxf(t, __shfl_xor(t, 2, 64));
      t = fmaxf(t, __shfl_xor(t, 4, 64));
      t = fmaxf(t, __shfl_xor(t, 8, 64));
      mnew[r] = fmaxf(mrow[r], t);
      alpha[r] = exp2f(mrow[r] - mnew[r]);
      mrow[r] = mnew[r];
    }
    float p[4][4];
#pragma unroll
    for (int n = 0; n < 4; ++n)
#pragma unroll
      for (int r = 0; r < 4; ++r) p[n][r] = exp2f(s[n][r] - mnew[r]);
#pragma unroll
    for (int r = 0; r < 4; ++r) {
      float rs = (p[0][r] + p[1][r]) + (p[2][r] + p[3][r]);
      rs += __shfl_xor(rs, 1, 64);
      rs += __shfl_xor(rs, 2, 64);
      rs += __shfl_xor(rs, 4, 64);
      rs += __shfl_xor(rs, 8, 64);
      lsum[r] = lsum[r] * alpha[r] + rs;
    }
#pragma unroll
    for (int f = 0; f < 4; ++f)
#pragma unroll
      for (int r = 0; r < 4; ++r) o[f][r] *= alpha[r];
    // P -> LDS (bf16), then re-read as A-fragments (transpose across lanes)
#pragma unroll
    for (int n = 0; n < 4; ++n)
#pragma unroll
      for (int r = 0; r < 4; ++r) Pl[w][lg * 4 + r][n * 16 + lr] = f2bf(p[n][r]);
    short8 pa0 = *(const short8*)((const char*)&Pl[w][lr][0] + lg * 16);
    short8 pa1 = *(const short8*)((const char*)&Pl[w][lr][32] + lg * 16);
    // O += P V  (V^T rows are d, contiguous in j)
#pragma unroll
    for (int f = 0; f < 4; ++f) {
      const u16* vp = vb + (size_t)(f * 16 + lr) * 4096 + j0 + lg * 8;
      short8 v0 = *(const short8*)vp;
      short8 v1 = *(const short8*)(vp + 32);
      o[f] = __builtin_amdgcn_mfma_f32_16x16x32_bf16(pa0, v0, o[f], 0, 0, 0);
      o[f] = __builtin_amdgcn_mfma_f32_16x16x32_bf16(pa1, v1, o[f], 0, 0, 0);
    }
  }
  const float hs = exp2f(-(float)h * LOG2PHI);  // phi^-h
#pragma unroll
  for (int r = 0; r < 4; ++r) {
    const float sc = hs / lsum[r];
    const int row = qrow0 + lg * 4 + r;
#pragma unroll
    for (int f = 0; f < 4; ++f)
      O[(size_t)row * 1024 + h * 64 + f * 16 + lr] = f2bf(o[f][r] * sc);
  }
}

extern "C" void kernel_launch(void* const* d_in, const int* in_sizes, int n_in,
                              void* d_out, int out_size, void* d_ws, size_t ws_size,
                              hipStream_t stream) {
  const float* x = (const float*)d_in[0];
  const float* Wq = (const float*)d_in[1];
  const float* bq = (const float*)d_in[2];
  const float* Wk = (const float*)d_in[3];
  const float* bk = (const float*)d_in[4];
  const float* Wv = (const float*)d_in[5];
  const float* bv = (const float*)d_in[6];
  const float* Wo = (const float*)d_in[7];
  const float* bo = (const float*)d_in[8];
  float* out = (float*)d_out;

  // ws layout (u16 elems): xb 4M | wqkv 3M | wob 1M | qs 4M | ks 4M | vt 4M
  // ob aliases xb (x no longer needed after QKV GEMM). Total 32 MB + none extra.
  u16* xb = (u16*)d_ws;
  u16* wqkv = xb + 4194304;
  u16* wob = wqkv + 3145728;
  u16* qs = wob + 1048576;
  u16* ks = qs + 4194304;
  u16* vt = ks + 4194304;
  u16* ob = xb;  // reuse

  cvt_kernel<<<4096, 256, 0, stream>>>(x, xb, 1048576);
  cvt_kernel<<<1024, 256, 0, stream>>>(Wq, wqkv, 262144);
  cvt_kernel<<<1024, 256, 0, stream>>>(Wk, wqkv + 1048576, 262144);
  cvt_kernel<<<1024, 256, 0, stream>>>(Wv, wqkv + 2097152, 262144);
  cvt_kernel<<<1024, 256, 0, stream>>>(Wo, wob, 262144);

  gemm_bt<0><<<dim3(32, 24), 256, 0, stream>>>(xb, wqkv, bq, bk, bv, qs, ks, vt, nullptr);
  attn_kernel<<<1024, 256, 0, stream>>>(qs, ks, vt, ob);
  gemm_bt<1><<<dim3(32, 8), 256, 0, stream>>>(ob, wob, bo, nullptr, nullptr,
                                              nullptr, nullptr, nullptr, out);
}